// Round 4
// baseline (483.218 us; speedup 1.0000x reference)
//
#include <hip/hip_runtime.h>
#include <math.h>

#define N_ 1024
#define ROWS_PER_DIR 65536   // B*N = 64*1024
#define TOTAL_ROWS   131072  // 2 directions
#define WAVES_PER_BLOCK 8
#define ROWS_PER_WAVE   2
#define ROWS_PER_BLOCK  (WAVES_PER_BLOCK * ROWS_PER_WAVE)      // 16
#define BLOCKS_K1       (TOTAL_ROWS / ROWS_PER_BLOCK)          // 8192
#define BLOCKS_PER_DIR  (BLOCKS_K1 / 2)                        // 4096

typedef float v4f __attribute__((ext_vector_type(4)));
typedef float v2f __attribute__((ext_vector_type(2)));

__device__ __forceinline__ float lane_max16(v4f v0, v4f v1, v4f v2, v4f v3) {
    v4f a = v0;
    a.x = fmaxf(a.x, v1.x); a.y = fmaxf(a.y, v1.y); a.z = fmaxf(a.z, v1.z); a.w = fmaxf(a.w, v1.w);
    v4f c = v2;
    c.x = fmaxf(c.x, v3.x); c.y = fmaxf(c.y, v3.y); c.z = fmaxf(c.z, v3.z); c.w = fmaxf(c.w, v3.w);
    a.x = fmaxf(a.x, c.x); a.y = fmaxf(a.y, c.y); a.z = fmaxf(a.z, c.z); a.w = fmaxf(a.w, c.w);
    return fmaxf(fmaxf(a.x, a.y), fmaxf(a.z, a.w));
}

__device__ __forceinline__ float lane_sumexp16(v4f v0, v4f v1, v4f v2, v4f v3, float m) {
    float s = 0.0f;
    s += __expf(v0.x - m); s += __expf(v0.y - m); s += __expf(v0.z - m); s += __expf(v0.w - m);
    s += __expf(v1.x - m); s += __expf(v1.y - m); s += __expf(v1.z - m); s += __expf(v1.w - m);
    s += __expf(v2.x - m); s += __expf(v2.y - m); s += __expf(v2.z - m); s += __expf(v2.w - m);
    s += __expf(v3.x - m); s += __expf(v3.y - m); s += __expf(v3.z - m); s += __expf(v3.w - m);
    return s;
}

// Kernel 1: one wave handles TWO consecutive rows (8 float4 loads in flight,
// two independent reduction chains for ILP). Two-phase reduction per row;
// target element extracted from registers + broadcast (no global re-read).
// Blocks are direction-uniform; valid-line count piggybacks on dir==0 blocks.
__global__ __launch_bounds__(512) void row_loss_kernel(
    const float* __restrict__ succ_logits,
    const int*   __restrict__ succ_labels,
    const float* __restrict__ pred_logits,
    const int*   __restrict__ pred_labels,
    const int*   __restrict__ line_mask,
    v2f*         __restrict__ partials)   // [BLOCKS_K1] (nll_sum, valid_cnt)
{
    __shared__ float wsum[WAVES_PER_BLOCK];
    __shared__ float wcnt[WAVES_PER_BLOCK];
    const int wave = threadIdx.x >> 6;
    const int lane = threadIdx.x & 63;
    const int dir  = blockIdx.x >= BLOCKS_PER_DIR;          // block-uniform
    const int rA   = (blockIdx.x & (BLOCKS_PER_DIR - 1)) * ROWS_PER_BLOCK
                   + wave * ROWS_PER_WAVE;                  // even, in [0, 65536)
    const int rB   = rA + 1;
    const int nA   = rA & (N_ - 1);
    const int nB   = nA + 1;                                // same batch row pair

    const float* __restrict__ logits = dir ? pred_logits : succ_logits;
    const int*   __restrict__ labels = dir ? pred_labels : succ_labels;
    const float* __restrict__ rowA   = logits + (size_t)rA * N_;
    const float* __restrict__ rowB   = logits + (size_t)rB * N_;

    // wave-uniform metadata first (one cacheline, broadcast)
    const int labelA = labels[rA], labelB = labels[rB];
    const int validA = line_mask[rA], validB = line_mask[rB];

    // 8 coalesced nontemporal float4 loads, all in flight together
    const v4f* rowA4 = (const v4f*)rowA;
    const v4f* rowB4 = (const v4f*)rowB;
    v4f a0 = __builtin_nontemporal_load(rowA4 + 0 * 64 + lane);
    v4f a1 = __builtin_nontemporal_load(rowA4 + 1 * 64 + lane);
    v4f a2 = __builtin_nontemporal_load(rowA4 + 2 * 64 + lane);
    v4f a3 = __builtin_nontemporal_load(rowA4 + 3 * 64 + lane);
    v4f b0 = __builtin_nontemporal_load(rowB4 + 0 * 64 + lane);
    v4f b1 = __builtin_nontemporal_load(rowB4 + 1 * 64 + lane);
    v4f b2 = __builtin_nontemporal_load(rowB4 + 2 * 64 + lane);
    v4f b3 = __builtin_nontemporal_load(rowB4 + 3 * 64 + lane);

    // target indices (diagonal if self-pointing, else clamped label)
    const int tA = (labelA == -1) ? nA : (labelA < 0 ? 0 : (labelA > N_ - 1 ? N_ - 1 : labelA));
    const int tB = (labelB == -1) ? nB : (labelB < 0 ? 0 : (labelB > N_ - 1 ? N_ - 1 : labelB));
    v4f tvA = ((tA >> 8) == 0) ? a0 : ((tA >> 8) == 1) ? a1 : ((tA >> 8) == 2) ? a2 : a3;
    v4f tvB = ((tB >> 8) == 0) ? b0 : ((tB >> 8) == 1) ? b1 : ((tB >> 8) == 2) ? b2 : b3;
    const float xA = __shfl(tvA[tA & 3], (tA >> 2) & 63);
    const float xB = __shfl(tvB[tB & 3], (tB >> 2) & 63);

    // phase 1: row maxes (two independent shuffle chains, interleaved by scheduler)
    float mA = lane_max16(a0, a1, a2, a3);
    float mB = lane_max16(b0, b1, b2, b3);
    #pragma unroll
    for (int off = 32; off > 0; off >>= 1) {
        mA = fmaxf(mA, __shfl_xor(mA, off));
        mB = fmaxf(mB, __shfl_xor(mB, off));
    }

    // phase 2: sum-exp at global max (two independent chains)
    float sA = lane_sumexp16(a0, a1, a2, a3, mA);
    float sB = lane_sumexp16(b0, b1, b2, b3, mB);
    #pragma unroll
    for (int off = 32; off > 0; off >>= 1) {
        sA += __shfl_xor(sA, off);
        sB += __shfl_xor(sB, off);
    }

    if (lane == 0) {
        float nll = 0.0f;
        if (validA) {
            if (labelA == -1)
                nll += __logf((sA - __expf(xA - mA)) * 0.36787944117144233f + 1.0f);
            else
                nll += mA + __logf(sA) - xA;
        }
        if (validB) {
            if (labelB == -1)
                nll += __logf((sB - __expf(xB - mB)) * 0.36787944117144233f + 1.0f);
            else
                nll += mB + __logf(sB) - xB;
        }
        wsum[wave] = nll;
        wcnt[wave] = (dir == 0) ? (float)((validA ? 1 : 0) + (validB ? 1 : 0)) : 0.0f;
    }
    __syncthreads();
    if (threadIdx.x == 0) {
        float acc = 0.0f, cnt = 0.0f;
        #pragma unroll
        for (int w = 0; w < WAVES_PER_BLOCK; ++w) { acc += wsum[w]; cnt += wcnt[w]; }
        v2f p; p.x = acc; p.y = cnt;
        partials[blockIdx.x] = p;   // temporal store: finalize reads from cache
    }
}

// Kernel 2: single-block deterministic finalize over 64 KiB of partials.
__global__ __launch_bounds__(1024) void finalize_kernel(
    const v2f*   __restrict__ partials,     // [BLOCKS_K1]
    const float* __restrict__ pred_weight,
    float*       __restrict__ out)
{
    const int tid = threadIdx.x;
    float ssum = 0.0f, psum = 0.0f, msum = 0.0f;
    for (int i = tid; i < BLOCKS_PER_DIR; i += 1024) {
        v2f sp = partials[i];
        v2f pp = partials[i + BLOCKS_PER_DIR];
        ssum += sp.x;
        msum += sp.y;
        psum += pp.x;
    }

    #pragma unroll
    for (int off = 32; off > 0; off >>= 1) {
        ssum += __shfl_xor(ssum, off);
        psum += __shfl_xor(psum, off);
        msum += __shfl_xor(msum, off);
    }

    __shared__ float sh[3][16];
    const int wave = tid >> 6, lane = tid & 63;
    if (lane == 0) { sh[0][wave] = ssum; sh[1][wave] = psum; sh[2][wave] = msum; }
    __syncthreads();
    if (tid == 0) {
        float S = 0.0f, P = 0.0f, M = 0.0f;
        #pragma unroll
        for (int w = 0; w < 16; ++w) { S += sh[0][w]; P += sh[1][w]; M += sh[2][w]; }
        const float denom = fmaxf(M, 1.0f);
        const float sl = S / denom, pl = P / denom;
        const float w  = pred_weight[0];
        out[0] = sl + w * pl;   // total_loss
        out[1] = sl;            // succ_loss
        out[2] = pl;            // pred_loss
        out[3] = M;             // num_valid
    }
}

extern "C" void kernel_launch(void* const* d_in, const int* in_sizes, int n_in,
                              void* d_out, int out_size, void* d_ws, size_t ws_size,
                              hipStream_t stream) {
    const float* succ_logits = (const float*)d_in[0];
    const int*   succ_labels = (const int*)  d_in[1];
    const float* pred_logits = (const float*)d_in[2];
    const int*   pred_labels = (const int*)  d_in[3];
    const int*   line_mask   = (const int*)  d_in[4];
    const float* pred_weight = (const float*)d_in[5];
    float* out      = (float*)d_out;
    v2f*   partials = (v2f*)d_ws;   // 8192 float2 = 64 KiB

    row_loss_kernel<<<BLOCKS_K1, 512, 0, stream>>>(
        succ_logits, succ_labels, pred_logits, pred_labels, line_mask, partials);
    finalize_kernel<<<1, 1024, 0, stream>>>(partials, pred_weight, out);
}